// Round 11
// baseline (177.046 us; speedup 1.0000x reference)
//
#include <hip/hip_runtime.h>
#include <hip/hip_bf16.h>
#include <stdint.h>

typedef __attribute__((ext_vector_type(8))) __bf16 bf16x8;
typedef __attribute__((ext_vector_type(4))) __bf16 bf16x4;
typedef __attribute__((ext_vector_type(4))) float f32x4;

static __device__ __forceinline__ ushort f2bf(float f) {
  union { float f; uint32_t u; } v; v.f = f;
  uint32_t u = v.u;
  u += 0x7fffu + ((u >> 16) & 1u);
  return (ushort)(u >> 16);
}

// async global->LDS, 16B per lane; lds dest must be wave-uniform base
static __device__ __forceinline__ void gl_lds16(const ushort* g, ushort* l) {
  __builtin_amdgcn_global_load_lds(
      (__attribute__((address_space(1))) unsigned int*)(g),
      (__attribute__((address_space(3))) unsigned int*)(l), 16, 0, 0);
}

// ---------------- cast x (fp32) -> bf16, same layout ----------------
__global__ __launch_bounds__(256) void cast_f32_bf16(
    const float* __restrict__ in, ushort* __restrict__ out, int n) {
  int i = (blockIdx.x * 256 + threadIdx.x) * 4;
  if (i >= n) return;
  float4 v = *(const float4*)&in[i];
  ushort4 o;
  o.x = f2bf(v.x); o.y = f2bf(v.y); o.z = f2bf(v.z); o.w = f2bf(v.w);
  *(ushort4*)&out[i] = o;
}

// ------------- transpose-cast W (K x N fp32) -> Wt (N x K bf16) -------------
__global__ __launch_bounds__(256) void transpose_cast(
    const float* __restrict__ W, ushort* __restrict__ Wt, int K, int N) {
  __shared__ ushort tile[32][33];
  int n0 = blockIdx.x * 32, k0 = blockIdx.y * 32;
  int tx = threadIdx.x, ty = threadIdx.y;
  #pragma unroll
  for (int r = ty; r < 32; r += 8)
    tile[r][tx] = f2bf(W[(size_t)(k0 + r) * N + n0 + tx]);
  __syncthreads();
  #pragma unroll
  for (int r = ty; r < 32; r += 8)
    Wt[(size_t)(n0 + r) * K + k0 + tx] = tile[tx][r];
}

// ---------------- GEMM: C[M,N] = A[M,K] * Bt[N,K]^T (bf16 in, fp32 acc) ------
// BM=256, BN=128, BK=64; 512 threads = 8 waves (2 Mwave x 4 Nwave), per-wave
// C 128x32. Double-buffered LDS (96 KB, 1 block/CU). 4 phases per K-tile
// (row quadrants), each phase: {stage one 8KB future region || ds_read ||
// lgkmcnt(0) || setprio MFMA x8 || barrier}. Counted vmcnt(5) ONCE per K-tile
// (6 loads/tile; 5 of next tile stay in flight). Stage region q is written in
// phase q+1, strictly after its readers' trailing barrier -> race-free.
// LDS chunk-XOR swizzle (chunk ^= row&7) with pre-swizzled global source.
// Requires M=8192, N mult of 128 with 1024-aligned Q/K/V split, K mult of 64.
// Grid 1D XCD-chunked: m0=((fid&7)*4+((fid>>3)&3))*256, n0=(fid>>5)*128.
// MODE 1: LDS-repack epilogue -> Q*SC (B,H,T,D), K (B,H,T,D), V^T (B,H,D,T)
// MODE 2: fp32 row-major C
template <int MODE>
__global__ __launch_bounds__(512, 2) void gemm_bt(
    const ushort* __restrict__ A, const ushort* __restrict__ Bt,
    float* __restrict__ Cf, int M, int N, int K,
    ushort* __restrict__ Qo, ushort* __restrict__ Ko, ushort* __restrict__ Vo) {
  __shared__ ushort smem[49152];  // A: [2][256][64] @0 | B: [2][128][64] @32768
  const int tid = threadIdx.x;
  const int lane = tid & 63;
  const int w = tid >> 6;
  const int wm = (w >> 2) * 128;  // 0 / 128
  const int wn = (w & 3) * 32;    // 0/32/64/96
  const int lr = lane & 15, kg = lane >> 4;
  const int fid = blockIdx.x;
  const int m0 = (((fid & 7) << 2) + ((fid >> 3) & 3)) << 8;
  const int n0 = (fid >> 5) << 7;

  // stage one 8KB region: A quarter q = rows {q*32..+31} u {128+q*32..+31};
  // B half h = rows {h*64..+63}. Lane: row += lane>>3, chunk = lane&7;
  // source pre-swizzled: srcchunk = (lane&7) ^ (lane>>3)  (row&7 == lane>>3).
  auto stageA = [&](int buf, int tile, int q) {
    const int k0 = tile << 6;
    const int rowb = q * 32 + (w >> 2) * 128 + (w & 3) * 8;
    gl_lds16(&A[(size_t)(m0 + rowb + (lane >> 3)) * K + k0 +
                (((lane & 7) ^ (lane >> 3)) << 3)],
             &smem[buf * 16384 + rowb * 64]);
  };
  auto stageB = [&](int buf, int tile, int h) {
    const int k0 = tile << 6;
    const int rowb = h * 64 + w * 8;
    gl_lds16(&Bt[(size_t)(n0 + rowb + (lane >> 3)) * K + k0 +
                 (((lane & 7) ^ (lane >> 3)) << 3)],
             &smem[32768 + buf * 8192 + rowb * 64]);
  };

  f32x4 zero = {0.f, 0.f, 0.f, 0.f};
  f32x4 acc[8][2];
  #pragma unroll
  for (int i = 0; i < 8; i++)
    #pragma unroll
    for (int j = 0; j < 2; j++) acc[i][j] = zero;

  // fragment-read swizzled chunk cols (ushort units): cg = ks*4 + kg
  const int cs0 = ((kg ^ (lr & 7)) << 3);
  const int cs1 = (((4 + kg) ^ (lr & 7)) << 3);

  const int nt = K >> 6;
  // prologue: tile0 fully (6 loads); tile1 minus A-q3 (5 loads)
  stageA(0, 0, 0); stageA(0, 0, 1); stageA(0, 0, 2); stageA(0, 0, 3);
  stageB(0, 0, 0); stageB(0, 0, 1);
  stageA(1, 1, 0); stageA(1, 1, 1); stageA(1, 1, 2);
  stageB(1, 1, 0); stageB(1, 1, 1);

  for (int t = 0; t < nt; ++t) {
    const int cur = t & 1, nxt = cur ^ 1;
    const int ab = cur * 16384, bb = 32768 + cur * 8192;
    // wait own tile-t loads (leave next tile's 5 in flight), sync all waves
    if (t + 1 < nt)
      asm volatile("s_waitcnt vmcnt(5)" ::: "memory");
    else
      asm volatile("s_waitcnt vmcnt(0)" ::: "memory");
    __builtin_amdgcn_s_barrier();
    asm volatile("" ::: "memory");
    // ---- phase 0: finish tile t+1 staging (its A-q3); B frags + A q0 ----
    if (t + 1 < nt) stageA(nxt, t + 1, 3);
    bf16x8 bfr[2][2], af[2][2];
    #pragma unroll
    for (int j = 0; j < 2; ++j) {
      const int R = wn + j * 16 + lr;
      bfr[j][0] = *(const bf16x8*)&smem[bb + R * 64 + cs0];
      bfr[j][1] = *(const bf16x8*)&smem[bb + R * 64 + cs1];
    }
    #pragma unroll
    for (int il = 0; il < 2; ++il) {
      const int R = wm + il * 16 + lr;
      af[il][0] = *(const bf16x8*)&smem[ab + R * 64 + cs0];
      af[il][1] = *(const bf16x8*)&smem[ab + R * 64 + cs1];
    }
    asm volatile("s_waitcnt lgkmcnt(0)" ::: "memory");
    __builtin_amdgcn_sched_barrier(0);
    __builtin_amdgcn_s_setprio(1);
    #pragma unroll
    for (int il = 0; il < 2; ++il)
      #pragma unroll
      for (int j = 0; j < 2; ++j) {
        acc[il][j] = __builtin_amdgcn_mfma_f32_16x16x32_bf16(
            af[il][0], bfr[j][0], acc[il][j], 0, 0, 0);
        acc[il][j] = __builtin_amdgcn_mfma_f32_16x16x32_bf16(
            af[il][1], bfr[j][1], acc[il][j], 0, 0, 0);
      }
    __builtin_amdgcn_s_setprio(0);
    __builtin_amdgcn_s_barrier();
    asm volatile("" ::: "memory");
    // ---- phases 1..3: stage tile t+2 regions (already-read quarters) ----
    #pragma unroll
    for (int p = 1; p < 4; ++p) {
      if (t + 2 < nt) {
        stageA(cur, t + 2, p - 1);
        if (p < 3) stageB(cur, t + 2, p - 1);
      }
      bf16x8 a2[2][2];
      #pragma unroll
      for (int il = 0; il < 2; ++il) {
        const int R = wm + (2 * p + il) * 16 + lr;
        a2[il][0] = *(const bf16x8*)&smem[ab + R * 64 + cs0];
        a2[il][1] = *(const bf16x8*)&smem[ab + R * 64 + cs1];
      }
      asm volatile("s_waitcnt lgkmcnt(0)" ::: "memory");
      __builtin_amdgcn_sched_barrier(0);
      __builtin_amdgcn_s_setprio(1);
      #pragma unroll
      for (int il = 0; il < 2; ++il)
        #pragma unroll
        for (int j = 0; j < 2; ++j) {
          acc[2 * p + il][j] = __builtin_amdgcn_mfma_f32_16x16x32_bf16(
              a2[il][0], bfr[j][0], acc[2 * p + il][j], 0, 0, 0);
          acc[2 * p + il][j] = __builtin_amdgcn_mfma_f32_16x16x32_bf16(
              a2[il][1], bfr[j][1], acc[2 * p + il][j], 0, 0, 0);
        }
      __builtin_amdgcn_s_setprio(0);
      __builtin_amdgcn_s_barrier();
      asm volatile("" ::: "memory");
    }
  }

  if (MODE == 2) {
    #pragma unroll
    for (int i = 0; i < 8; i++)
      #pragma unroll
      for (int j = 0; j < 2; j++)
        #pragma unroll
        for (int r = 0; r < 4; r++) {
          int mrow = m0 + wm + i * 16 + kg * 4 + r;
          int ncol = n0 + wn + j * 16 + lr;
          Cf[(size_t)mrow * N + ncol] = acc[i][j][r];
        }
  } else {
    // LDS-repack epilogue: per-wave 10KB area (alias staging LDS).
    __syncthreads();  // all waves done with staging LDS
    ushort* Ls = smem + w * 5120;
    const int nb = n0 + wn;
    const int which = nb >> 10;  // 0=Q 1=K 2=V (wave-uniform)
    const int bb2 = (m0 + wm) >> 11;
    const int hh = (nb & 1023) >> 6;
    const int d0 = nb & 63;  // 0 or 32
    const size_t bh = (size_t)(bb2 * 16 + hh);
    const int t0 = (m0 + wm) & 2047;
    if (which == 2) {
      // V transposed in LDS: [d 0..31][t 0..127], stride 136 (16B-mult rows)
      #pragma unroll
      for (int i = 0; i < 8; i++)
        #pragma unroll
        for (int j = 0; j < 2; j++)
          #pragma unroll
          for (int r = 0; r < 4; r++)
            Ls[(j * 16 + lr) * 136 + (i * 16 + kg * 4 + r)] =
                f2bf(acc[i][j][r]);
      #pragma unroll
      for (int it = 0; it < 8; it++) {
        const int cid = it * 64 + lane;
        const int d = cid >> 4, chk = cid & 15;
        bf16x8 v = *(const bf16x8*)&Ls[d * 136 + chk * 8];
        *(bf16x8*)&Vo[(bh * 64 + d0 + d) * 2048 + t0 + chk * 8] = v;
      }
    } else {
      const float sc = (which == 0) ? 0.18033688011112042f : 1.0f;
      // [t 0..127][d 0..31], stride 40 (80B rows, 16B-mult)
      #pragma unroll
      for (int i = 0; i < 8; i++)
        #pragma unroll
        for (int j = 0; j < 2; j++)
          #pragma unroll
          for (int r = 0; r < 4; r++)
            Ls[(i * 16 + kg * 4 + r) * 40 + (j * 16 + lr)] =
                f2bf(acc[i][j][r] * sc);
      ushort* dst = (which == 0) ? Qo : Ko;
      #pragma unroll
      for (int it = 0; it < 8; it++) {
        const int cid = it * 64 + lane;
        const int row = cid >> 2, chk = cid & 3;
        bf16x8 v = *(const bf16x8*)&Ls[row * 40 + chk * 8];
        *(bf16x8*)&dst[(bh * 2048 + t0 + row) * 64 + d0 + chk * 8] = v;
      }
    }
  }
}

// ------- flash attention (causal), 4 waves/block sharing K/V via LDS --------
// QBLK=16/wave, 64-row blocks, grid 1024 = 4 blocks/CU (16 waves/CU).
// No-max softmax (Q pre-scaled), 2-phase double-buffered K/V staging.
// Q,K: (B*H, T, D) bf16 ; Vt: (B*H, D, T) bf16 ; Y: (B, T, C) bf16
__global__ __launch_bounds__(256, 4) void attn_fwd(
    const ushort* __restrict__ Q, const ushort* __restrict__ Kc,
    const ushort* __restrict__ Vt, ushort* __restrict__ Y) {
  __shared__ ushort Ks[2][64][64];  // [k][d], 16B-chunk XOR-swizzled
  __shared__ ushort Vs[2][64][64];  // [d][k], 16B-chunk XOR-swizzled
  __shared__ ushort Ps[4][16][64];  // per-wave P, [q][k], XOR-swizzled
  const int tid = threadIdx.x;
  const int lane = tid & 63, w = tid >> 6;
  const int lr = lane & 15, kg = lane >> 4;
  int blk = blockIdx.x;
  blk = (blk & 7) * 128 + (blk >> 3);  // XCD-chunked (1024 % 8 == 0)
  const int pair = blk & 15;
  const int bh = blk >> 4;
  const ushort* Qp = Q + (size_t)bh * 2048 * 64;
  const ushort* Kp = Kc + (size_t)bh * 2048 * 64;
  const ushort* Vp = Vt + (size_t)bh * 64 * 2048;
  const int b = bh >> 4, h = bh & 15;
  const int swz = (lr & 14) << 3;  // P-tile swizzle (bytes)
  char* PsB = (char*)&Ps[w][0][0];
  const int srow = lane >> 3, schunk = lane & 7;
  const int cs0 = (kg ^ (lr & 7)) << 3;
  const int cs1 = ((kg ^ 4) ^ (lr & 7)) << 3;
  f32x4 zero = {0.f, 0.f, 0.f, 0.f};

  auto stageKV = [&](int buf, int k0) {
    #pragma unroll
    for (int c = 0; c < 2; c++) {
      const int rbase = w * 16 + c * 8;
      const int r = rbase + srow;
      gl_lds16(&Kp[(size_t)(k0 + r) * 64 + ((schunk ^ (r & 7)) << 3)],
               &Ks[buf][rbase][0]);
      gl_lds16(&Vp[(size_t)r * 2048 + k0 + ((schunk ^ (r & 7)) << 3)],
               &Vs[buf][rbase][0]);
    }
  };

  for (int half = 0; half < 2; half++) {
    const int j = half ? (31 - pair) : pair;
    const int q0b = j << 6;
    const int qw0 = q0b + w * 16;
    bf16x8 qf0 = *(const bf16x8*)&Qp[(size_t)(qw0 + lr) * 64 + kg * 8];
    bf16x8 qf1 = *(const bf16x8*)&Qp[(size_t)(qw0 + lr) * 64 + 32 + kg * 8];
    f32x4 o[4];
    #pragma unroll
    for (int dt = 0; dt < 4; dt++) o[dt] = zero;
    float lsum = 0.f;

    stageKV(0, 0);
    __syncthreads();  // prologue KV tile resident
    for (int k0 = 0; k0 <= q0b; k0 += 64) {
      const int cur = (k0 >> 6) & 1;
      if (k0 < q0b) stageKV(cur ^ 1, k0 + 64);  // in flight over compute

      // S^T tile: mfma(K-rows, Q-rows) -> C[k][q], lane holds q = lr
      f32x4 s[4];
      #pragma unroll
      for (int ct = 0; ct < 4; ct++) {
        bf16x8 kf0 = *(const bf16x8*)&Ks[cur][ct * 16 + lr][cs0];
        bf16x8 kf1 = *(const bf16x8*)&Ks[cur][ct * 16 + lr][cs1];
        f32x4 z = zero;
        z = __builtin_amdgcn_mfma_f32_16x16x32_bf16(kf0, qf0, z, 0, 0, 0);
        z = __builtin_amdgcn_mfma_f32_16x16x32_bf16(kf1, qf1, z, 0, 0, 0);
        s[ct] = z;
      }
      if (k0 == q0b) {  // only the last block needs the causal mask
        const int qrow = qw0 + lr;
        #pragma unroll
        for (int ct = 0; ct < 4; ct++)
          #pragma unroll
          for (int r = 0; r < 4; r++) {
            int kj = k0 + ct * 16 + kg * 4 + r;
            s[ct][r] = (kj > qrow) ? -1e30f : s[ct][r];
          }
      }
      // p = exp2(s); accumulate l per-lane (reduced once per tile); pack bf16
      #pragma unroll
      for (int ct = 0; ct < 4; ct++) {
        float p0 = exp2f(s[ct][0]);
        float p1 = exp2f(s[ct][1]);
        float p2 = exp2f(s[ct][2]);
        float p3 = exp2f(s[ct][3]);
        lsum += (p0 + p1) + (p2 + p3);
        bf16x4 pk = {(__bf16)p0, (__bf16)p1, (__bf16)p2, (__bf16)p3};
        *(bf16x4*)(PsB + lr * 128 + ((ct * 32 + kg * 8) ^ swz)) = pk;
      }
      bf16x8 pa0 = *(const bf16x8*)(PsB + lr * 128 + ((kg * 16) ^ swz));
      bf16x8 pa1 = *(const bf16x8*)(PsB + lr * 128 + ((64 + kg * 16) ^ swz));
      #pragma unroll
      for (int dt = 0; dt < 4; dt++) {
        bf16x8 vf0 = *(const bf16x8*)&Vs[cur][dt * 16 + lr][cs0];
        bf16x8 vf1 = *(const bf16x8*)&Vs[cur][dt * 16 + lr][cs1];
        f32x4 t = o[dt];
        t = __builtin_amdgcn_mfma_f32_16x16x32_bf16(pa0, vf0, t, 0, 0, 0);
        t = __builtin_amdgcn_mfma_f32_16x16x32_bf16(pa1, vf1, t, 0, 0, 0);
        o[dt] = t;
      }
      __syncthreads();  // drains vmcnt (next KV ready) + protects reads
    }

    // epilogue: reduce l across the 4 lanes of each row, divide, write Y
    lsum += __shfl_xor(lsum, 16);
    lsum += __shfl_xor(lsum, 32);
    float inv = 1.f / lsum;
    f32x4 ib;
    #pragma unroll
    for (int r = 0; r < 4; r++) ib[r] = __shfl(inv, kg * 4 + r);
    #pragma unroll
    for (int dt = 0; dt < 4; dt++) {
      #pragma unroll
      for (int r = 0; r < 4; r++) {
        size_t t = (size_t)qw0 + kg * 4 + r;
        Y[((size_t)b * 2048 + t) * 1024 + h * 64 + dt * 16 + lr] =
            f2bf(o[dt][r] * ib[r]);
      }
    }
  }
}

extern "C" void kernel_launch(void* const* d_in, const int* in_sizes, int n_in,
                              void* d_out, int out_size, void* d_ws,
                              size_t ws_size, hipStream_t stream) {
  const float* x = (const float*)d_in[0];
  const float* Wa = (const float*)d_in[1];
  const float* Wp = (const float*)d_in[2];
  float* out = (float*)d_out;

  char* ws = (char*)d_ws;
  size_t off = 0;
  auto carve = [&](size_t bytes) {
    void* p = ws + off;
    off += (bytes + 255) & ~(size_t)255;
    return p;
  };
  ushort* Xb = (ushort*)carve(8192ull * 1024 * 2);
  ushort* Wat = (ushort*)carve(3072ull * 1024 * 2);
  ushort* Wpt = (ushort*)carve(1024ull * 1024 * 2);
  ushort* Qh = (ushort*)carve(64ull * 2048 * 64 * 2);
  ushort* Kh = (ushort*)carve(64ull * 2048 * 64 * 2);
  ushort* Vt = (ushort*)carve(64ull * 64 * 2048 * 2);
  ushort* Yb = (ushort*)carve(8192ull * 1024 * 2);

  cast_f32_bf16<<<8192, 256, 0, stream>>>(x, Xb, 8192 * 1024);
  transpose_cast<<<dim3(96, 32), dim3(32, 8), 0, stream>>>(Wa, Wat, 1024, 3072);
  transpose_cast<<<dim3(32, 32), dim3(32, 8), 0, stream>>>(Wp, Wpt, 1024, 1024);
  gemm_bt<1><<<768, 512, 0, stream>>>(Xb, Wat, nullptr, 8192, 3072, 1024, Qh,
                                      Kh, Vt);
  attn_fwd<<<1024, 256, 0, stream>>>(Qh, Kh, Vt, Yb);
  gemm_bt<2><<<256, 512, 0, stream>>>(Yb, Wpt, out, 8192, 1024, 1024, nullptr,
                                      nullptr, nullptr);
}

// Round 12
// 169.124 us; speedup vs baseline: 1.0468x; 1.0468x over previous
//
#include <hip/hip_runtime.h>
#include <hip/hip_bf16.h>
#include <stdint.h>

typedef __attribute__((ext_vector_type(8))) __bf16 bf16x8;
typedef __attribute__((ext_vector_type(4))) __bf16 bf16x4;
typedef __attribute__((ext_vector_type(4))) float f32x4;

static __device__ __forceinline__ ushort f2bf(float f) {
  union { float f; uint32_t u; } v; v.f = f;
  uint32_t u = v.u;
  u += 0x7fffu + ((u >> 16) & 1u);
  return (ushort)(u >> 16);
}

// async global->LDS, 16B per lane; lds dest must be wave-uniform base
static __device__ __forceinline__ void gl_lds16(const ushort* g, ushort* l) {
  __builtin_amdgcn_global_load_lds(
      (__attribute__((address_space(1))) unsigned int*)(g),
      (__attribute__((address_space(3))) unsigned int*)(l), 16, 0, 0);
}

// ---------------- cast x (fp32) -> bf16, same layout ----------------
__global__ __launch_bounds__(256) void cast_f32_bf16(
    const float* __restrict__ in, ushort* __restrict__ out, int n) {
  int i = (blockIdx.x * 256 + threadIdx.x) * 4;
  if (i >= n) return;
  float4 v = *(const float4*)&in[i];
  ushort4 o;
  o.x = f2bf(v.x); o.y = f2bf(v.y); o.z = f2bf(v.z); o.w = f2bf(v.w);
  *(ushort4*)&out[i] = o;
}

// ------------- transpose-cast W (K x N fp32) -> Wt (N x K bf16) -------------
__global__ __launch_bounds__(256) void transpose_cast(
    const float* __restrict__ W, ushort* __restrict__ Wt, int K, int N) {
  __shared__ ushort tile[32][33];
  int n0 = blockIdx.x * 32, k0 = blockIdx.y * 32;
  int tx = threadIdx.x, ty = threadIdx.y;
  #pragma unroll
  for (int r = ty; r < 32; r += 8)
    tile[r][tx] = f2bf(W[(size_t)(k0 + r) * N + n0 + tx]);
  __syncthreads();
  #pragma unroll
  for (int r = ty; r < 32; r += 8)
    Wt[(size_t)(n0 + r) * K + k0 + tx] = tile[tx][r];
}

// ---------------- GEMM: C[M,N] = A[M,K] * Bt[N,K]^T (bf16 in, fp32 acc) ------
// BM=128, BN=128, BK=64; 256 threads = 4 waves (2Mx2N), per-wave C 64x64.
// LDS 64KB double-buffered -> 2 blocks/CU (independent blocks hide each
// other's barrier/drain stalls). 2 phases per K-tile, 16 MFMA each; B frags
// register-resident across phases (16 b128 per 32 MFMA). Counted vmcnt(4)
// once per tile (8 loads/tile; next tile's 4 stay in flight, never 0 in main
// loop). Stage A(t+1) in ph0, B(t+2) in ph1 -- each write lands strictly
// after its buffer's readers' trailing barrier. Chunk-XOR LDS swizzle with
// pre-swizzled global source (2 lanes/bank on b128 reads = wave64 minimum).
// Grid 1D XCD-chunked m-fast: m0=((fid&7)*8+((fid>>3)&7))*128, n0=(fid>>6)*128.
// MODE 1: LDS-repack epilogue -> Q*SC (B,H,T,D), K (B,H,T,D), V^T (B,H,D,T)
// MODE 2: fp32 row-major C
template <int MODE>
__global__ __launch_bounds__(256, 2) void gemm_bt(
    const ushort* __restrict__ A, const ushort* __restrict__ Bt,
    float* __restrict__ Cf, int M, int N, int K,
    ushort* __restrict__ Qo, ushort* __restrict__ Ko, ushort* __restrict__ Vo) {
  __shared__ ushort smem[32768];  // A:[2][128][64]@0 | B:[2][128][64]@16384
  const int tid = threadIdx.x;
  const int lane = tid & 63;
  const int w = tid >> 6;         // 4 waves
  const int wm = (w >> 1) * 64, wn = (w & 1) * 64;
  const int lr = lane & 15, kg = lane >> 4;
  const int fid = blockIdx.x;
  const int m0 = (((fid & 7) << 3) + ((fid >> 3) & 7)) << 7;
  const int n0 = (fid >> 6) << 7;

  // stage one 4KB region (32 rows): wave w covers rows rowb..rowb+7,
  // lane: row += lane>>3, chunk = lane&7; source pre-swizzled chunk^row&7.
  auto stageA = [&](int buf, int tile, int q) {
    const int k0 = tile << 6;
    const int rowb = q * 32 + w * 8;
    gl_lds16(&A[(size_t)(m0 + rowb + (lane >> 3)) * K + k0 +
                (((lane & 7) ^ (lane >> 3)) << 3)],
             &smem[buf * 8192 + rowb * 64]);
  };
  auto stageB = [&](int buf, int tile, int q) {
    const int k0 = tile << 6;
    const int rowb = q * 32 + w * 8;
    gl_lds16(&Bt[(size_t)(n0 + rowb + (lane >> 3)) * K + k0 +
                 (((lane & 7) ^ (lane >> 3)) << 3)],
             &smem[16384 + buf * 8192 + rowb * 64]);
  };

  f32x4 zero = {0.f, 0.f, 0.f, 0.f};
  f32x4 acc[4][4];
  #pragma unroll
  for (int i = 0; i < 4; i++)
    #pragma unroll
    for (int j = 0; j < 4; j++) acc[i][j] = zero;

  // fragment-read swizzled chunk offsets (ushort units)
  const int cs0 = ((kg ^ (lr & 7)) << 3);
  const int cs1 = (((4 + kg) ^ (lr & 7)) << 3);

  const int nt = K >> 6;
  // prologue order: B(0)x4, A(0)x4, B(1)x4  -> vmcnt(4) uniform at loop top
  stageB(0, 0, 0); stageB(0, 0, 1); stageB(0, 0, 2); stageB(0, 0, 3);
  stageA(0, 0, 0); stageA(0, 0, 1); stageA(0, 0, 2); stageA(0, 0, 3);
  stageB(1, 1, 0); stageB(1, 1, 1); stageB(1, 1, 2); stageB(1, 1, 3);

  for (int t = 0; t < nt; ++t) {
    const int cur = t & 1, nxt = cur ^ 1;
    const int ab = cur * 8192, bbo = 16384 + cur * 8192;
    // wait own tile-t loads (leave next tile's 4 in flight), sync all waves
    if (t + 1 < nt)
      asm volatile("s_waitcnt vmcnt(4)" ::: "memory");
    else
      asm volatile("s_waitcnt vmcnt(0)" ::: "memory");
    __builtin_amdgcn_s_barrier();
    asm volatile("" ::: "memory");
    // ---- phase 0: stage A(t+1); B frags (all) + A row-tiles 0,1 ----
    if (t + 1 < nt) {
      stageA(nxt, t + 1, 0); stageA(nxt, t + 1, 1);
      stageA(nxt, t + 1, 2); stageA(nxt, t + 1, 3);
    }
    bf16x8 bfr[4][2], af[2][2];
    #pragma unroll
    for (int j = 0; j < 4; ++j) {
      const int R = wn + j * 16 + lr;
      bfr[j][0] = *(const bf16x8*)&smem[bbo + R * 64 + cs0];
      bfr[j][1] = *(const bf16x8*)&smem[bbo + R * 64 + cs1];
    }
    #pragma unroll
    for (int il = 0; il < 2; ++il) {
      const int R = wm + il * 16 + lr;
      af[il][0] = *(const bf16x8*)&smem[ab + R * 64 + cs0];
      af[il][1] = *(const bf16x8*)&smem[ab + R * 64 + cs1];
    }
    asm volatile("s_waitcnt lgkmcnt(0)" ::: "memory");
    __builtin_amdgcn_sched_barrier(0);
    __builtin_amdgcn_s_setprio(1);
    #pragma unroll
    for (int il = 0; il < 2; ++il)
      #pragma unroll
      for (int j = 0; j < 4; ++j) {
        acc[il][j] = __builtin_amdgcn_mfma_f32_16x16x32_bf16(
            af[il][0], bfr[j][0], acc[il][j], 0, 0, 0);
        acc[il][j] = __builtin_amdgcn_mfma_f32_16x16x32_bf16(
            af[il][1], bfr[j][1], acc[il][j], 0, 0, 0);
      }
    __builtin_amdgcn_s_setprio(0);
    __builtin_amdgcn_s_barrier();
    asm volatile("" ::: "memory");
    // ---- phase 1: stage B(t+2) (B(cur) fully read in ph0); A rows 2,3 ----
    if (t + 2 < nt) {
      stageB(cur, t + 2, 0); stageB(cur, t + 2, 1);
      stageB(cur, t + 2, 2); stageB(cur, t + 2, 3);
    }
    bf16x8 a2[2][2];
    #pragma unroll
    for (int il = 0; il < 2; ++il) {
      const int R = wm + (2 + il) * 16 + lr;
      a2[il][0] = *(const bf16x8*)&smem[ab + R * 64 + cs0];
      a2[il][1] = *(const bf16x8*)&smem[ab + R * 64 + cs1];
    }
    asm volatile("s_waitcnt lgkmcnt(0)" ::: "memory");
    __builtin_amdgcn_sched_barrier(0);
    __builtin_amdgcn_s_setprio(1);
    #pragma unroll
    for (int il = 0; il < 2; ++il)
      #pragma unroll
      for (int j = 0; j < 4; ++j) {
        acc[2 + il][j] = __builtin_amdgcn_mfma_f32_16x16x32_bf16(
            a2[il][0], bfr[j][0], acc[2 + il][j], 0, 0, 0);
        acc[2 + il][j] = __builtin_amdgcn_mfma_f32_16x16x32_bf16(
            a2[il][1], bfr[j][1], acc[2 + il][j], 0, 0, 0);
      }
    __builtin_amdgcn_s_setprio(0);
    // loop-top barrier doubles as phase-1 trailing barrier
  }

  if (MODE == 2) {
    #pragma unroll
    for (int i = 0; i < 4; i++)
      #pragma unroll
      for (int j = 0; j < 4; j++)
        #pragma unroll
        for (int r = 0; r < 4; r++) {
          int mrow = m0 + wm + i * 16 + kg * 4 + r;
          int ncol = n0 + wn + j * 16 + lr;
          Cf[(size_t)mrow * N + ncol] = acc[i][j][r];
        }
  } else {
    // LDS-repack epilogue: per-wave 64x72 tile (alias staging LDS),
    // V transposed in LDS; then 8 coalesced 16B stores per lane.
    __syncthreads();  // all waves done with staging LDS
    ushort* Ls = smem + w * 4608;
    const int nb = n0 + wn;
    const int which = nb >> 10;  // 0=Q 1=K 2=V (wave-uniform, 64-wide = 1 head)
    const int bb2 = (m0 + wm) >> 11;
    const int hh = (nb & 1023) >> 6;
    const size_t bh = (size_t)(bb2 * 16 + hh);
    const int t0 = (m0 + wm) & 2047;
    if (which == 2) {
      // transposed: [d 0..63][t 0..63], stride 72
      #pragma unroll
      for (int i = 0; i < 4; i++)
        #pragma unroll
        for (int j = 0; j < 4; j++)
          #pragma unroll
          for (int r = 0; r < 4; r++)
            Ls[(j * 16 + lr) * 72 + (i * 16 + kg * 4 + r)] =
                f2bf(acc[i][j][r]);
      #pragma unroll
      for (int it = 0; it < 8; it++) {
        const int cid = it * 64 + lane;
        const int d = cid >> 3, chk = cid & 7;
        bf16x8 v = *(const bf16x8*)&Ls[d * 72 + chk * 8];
        *(bf16x8*)&Vo[(bh * 64 + d) * 2048 + t0 + chk * 8] = v;
      }
    } else {
      const float sc = (which == 0) ? 0.18033688011112042f : 1.0f;
      // [t 0..63][d 0..63], stride 72
      #pragma unroll
      for (int i = 0; i < 4; i++)
        #pragma unroll
        for (int j = 0; j < 4; j++)
          #pragma unroll
          for (int r = 0; r < 4; r++)
            Ls[(i * 16 + kg * 4 + r) * 72 + (j * 16 + lr)] =
                f2bf(acc[i][j][r] * sc);
      ushort* dst = (which == 0) ? Qo : Ko;
      #pragma unroll
      for (int it = 0; it < 8; it++) {
        const int cid = it * 64 + lane;
        const int row = cid >> 3, chk = cid & 7;
        bf16x8 v = *(const bf16x8*)&Ls[row * 72 + chk * 8];
        *(bf16x8*)&dst[(bh * 2048 + t0 + row) * 64 + chk * 8] = v;
      }
    }
  }
}

// ------- flash attention (causal), 4 waves/block sharing K/V via LDS --------
// QBLK=16/wave, 64-row blocks, grid 1024 = 4 blocks/CU (16 waves/CU).
// No-max softmax (Q pre-scaled), 2-phase double-buffered K/V staging.
// Q,K: (B*H, T, D) bf16 ; Vt: (B*H, D, T) bf16 ; Y: (B, T, C) bf16
__global__ __launch_bounds__(256, 4) void attn_fwd(
    const ushort* __restrict__ Q, const ushort* __restrict__ Kc,
    const ushort* __restrict__ Vt, ushort* __restrict__ Y) {
  __shared__ ushort Ks[2][64][64];  // [k][d], 16B-chunk XOR-swizzled
  __shared__ ushort Vs[2][64][64];  // [d][k], 16B-chunk XOR-swizzled
  __shared__ ushort Ps[4][16][64];  // per-wave P, [q][k], XOR-swizzled
  const int tid = threadIdx.x;
  const int lane = tid & 63, w = tid >> 6;
  const int lr = lane & 15, kg = lane >> 4;
  int blk = blockIdx.x;
  blk = (blk & 7) * 128 + (blk >> 3);  // XCD-chunked (1024 % 8 == 0)
  const int pair = blk & 15;
  const int bh = blk >> 4;
  const ushort* Qp = Q + (size_t)bh * 2048 * 64;
  const ushort* Kp = Kc + (size_t)bh * 2048 * 64;
  const ushort* Vp = Vt + (size_t)bh * 64 * 2048;
  const int b = bh >> 4, h = bh & 15;
  const int swz = (lr & 14) << 3;  // P-tile swizzle (bytes)
  char* PsB = (char*)&Ps[w][0][0];
  const int srow = lane >> 3, schunk = lane & 7;
  const int cs0 = (kg ^ (lr & 7)) << 3;
  const int cs1 = ((kg ^ 4) ^ (lr & 7)) << 3;
  f32x4 zero = {0.f, 0.f, 0.f, 0.f};

  auto stageKV = [&](int buf, int k0) {
    #pragma unroll
    for (int c = 0; c < 2; c++) {
      const int rbase = w * 16 + c * 8;
      const int r = rbase + srow;
      gl_lds16(&Kp[(size_t)(k0 + r) * 64 + ((schunk ^ (r & 7)) << 3)],
               &Ks[buf][rbase][0]);
      gl_lds16(&Vp[(size_t)r * 2048 + k0 + ((schunk ^ (r & 7)) << 3)],
               &Vs[buf][rbase][0]);
    }
  };

  for (int half = 0; half < 2; half++) {
    const int j = half ? (31 - pair) : pair;
    const int q0b = j << 6;
    const int qw0 = q0b + w * 16;
    bf16x8 qf0 = *(const bf16x8*)&Qp[(size_t)(qw0 + lr) * 64 + kg * 8];
    bf16x8 qf1 = *(const bf16x8*)&Qp[(size_t)(qw0 + lr) * 64 + 32 + kg * 8];
    f32x4 o[4];
    #pragma unroll
    for (int dt = 0; dt < 4; dt++) o[dt] = zero;
    float lsum = 0.f;

    stageKV(0, 0);
    __syncthreads();  // prologue KV tile resident
    for (int k0 = 0; k0 <= q0b; k0 += 64) {
      const int cur = (k0 >> 6) & 1;
      if (k0 < q0b) stageKV(cur ^ 1, k0 + 64);  // in flight over compute

      // S^T tile: mfma(K-rows, Q-rows) -> C[k][q], lane holds q = lr
      f32x4 s[4];
      #pragma unroll
      for (int ct = 0; ct < 4; ct++) {
        bf16x8 kf0 = *(const bf16x8*)&Ks[cur][ct * 16 + lr][cs0];
        bf16x8 kf1 = *(const bf16x8*)&Ks[cur][ct * 16 + lr][cs1];
        f32x4 z = zero;
        z = __builtin_amdgcn_mfma_f32_16x16x32_bf16(kf0, qf0, z, 0, 0, 0);
        z = __builtin_amdgcn_mfma_f32_16x16x32_bf16(kf1, qf1, z, 0, 0, 0);
        s[ct] = z;
      }
      if (k0 == q0b) {  // only the last block needs the causal mask
        const int qrow = qw0 + lr;
        #pragma unroll
        for (int ct = 0; ct < 4; ct++)
          #pragma unroll
          for (int r = 0; r < 4; r++) {
            int kj = k0 + ct * 16 + kg * 4 + r;
            s[ct][r] = (kj > qrow) ? -1e30f : s[ct][r];
          }
      }
      // p = exp2(s); accumulate l per-lane (reduced once per tile); pack bf16
      #pragma unroll
      for (int ct = 0; ct < 4; ct++) {
        float p0 = exp2f(s[ct][0]);
        float p1 = exp2f(s[ct][1]);
        float p2 = exp2f(s[ct][2]);
        float p3 = exp2f(s[ct][3]);
        lsum += (p0 + p1) + (p2 + p3);
        bf16x4 pk = {(__bf16)p0, (__bf16)p1, (__bf16)p2, (__bf16)p3};
        *(bf16x4*)(PsB + lr * 128 + ((ct * 32 + kg * 8) ^ swz)) = pk;
      }
      bf16x8 pa0 = *(const bf16x8*)(PsB + lr * 128 + ((kg * 16) ^ swz));
      bf16x8 pa1 = *(const bf16x8*)(PsB + lr * 128 + ((64 + kg * 16) ^ swz));
      #pragma unroll
      for (int dt = 0; dt < 4; dt++) {
        bf16x8 vf0 = *(const bf16x8*)&Vs[cur][dt * 16 + lr][cs0];
        bf16x8 vf1 = *(const bf16x8*)&Vs[cur][dt * 16 + lr][cs1];
        f32x4 t = o[dt];
        t = __builtin_amdgcn_mfma_f32_16x16x32_bf16(pa0, vf0, t, 0, 0, 0);
        t = __builtin_amdgcn_mfma_f32_16x16x32_bf16(pa1, vf1, t, 0, 0, 0);
        o[dt] = t;
      }
      __syncthreads();  // drains vmcnt (next KV ready) + protects reads
    }

    // epilogue: reduce l across the 4 lanes of each row, divide, write Y
    lsum += __shfl_xor(lsum, 16);
    lsum += __shfl_xor(lsum, 32);
    float inv = 1.f / lsum;
    f32x4 ib;
    #pragma unroll
    for (int r = 0; r < 4; r++) ib[r] = __shfl(inv, kg * 4 + r);
    #pragma unroll
    for (int dt = 0; dt < 4; dt++) {
      #pragma unroll
      for (int r = 0; r < 4; r++) {
        size_t t = (size_t)qw0 + kg * 4 + r;
        Y[((size_t)b * 2048 + t) * 1024 + h * 64 + dt * 16 + lr] =
            f2bf(o[dt][r] * ib[r]);
      }
    }
  }
}

extern "C" void kernel_launch(void* const* d_in, const int* in_sizes, int n_in,
                              void* d_out, int out_size, void* d_ws,
                              size_t ws_size, hipStream_t stream) {
  const float* x = (const float*)d_in[0];
  const float* Wa = (const float*)d_in[1];
  const float* Wp = (const float*)d_in[2];
  float* out = (float*)d_out;

  char* ws = (char*)d_ws;
  size_t off = 0;
  auto carve = [&](size_t bytes) {
    void* p = ws + off;
    off += (bytes + 255) & ~(size_t)255;
    return p;
  };
  ushort* Xb = (ushort*)carve(8192ull * 1024 * 2);
  ushort* Wat = (ushort*)carve(3072ull * 1024 * 2);
  ushort* Wpt = (ushort*)carve(1024ull * 1024 * 2);
  ushort* Qh = (ushort*)carve(64ull * 2048 * 64 * 2);
  ushort* Kh = (ushort*)carve(64ull * 2048 * 64 * 2);
  ushort* Vt = (ushort*)carve(64ull * 64 * 2048 * 2);
  ushort* Yb = (ushort*)carve(8192ull * 1024 * 2);

  cast_f32_bf16<<<8192, 256, 0, stream>>>(x, Xb, 8192 * 1024);
  transpose_cast<<<dim3(96, 32), dim3(32, 8), 0, stream>>>(Wa, Wat, 1024, 3072);
  transpose_cast<<<dim3(32, 32), dim3(32, 8), 0, stream>>>(Wp, Wpt, 1024, 1024);
  gemm_bt<1><<<1536, 256, 0, stream>>>(Xb, Wat, nullptr, 8192, 3072, 1024, Qh,
                                       Kh, Vt);
  attn_fwd<<<1024, 256, 0, stream>>>(Qh, Kh, Vt, Yb);
  gemm_bt<2><<<512, 256, 0, stream>>>(Yb, Wpt, out, 8192, 1024, 1024, nullptr,
                                      nullptr, nullptr);
}

// Round 13
// 155.574 us; speedup vs baseline: 1.1380x; 1.0871x over previous
//
#include <hip/hip_runtime.h>
#include <hip/hip_bf16.h>
#include <stdint.h>

typedef __attribute__((ext_vector_type(8))) __bf16 bf16x8;
typedef __attribute__((ext_vector_type(4))) __bf16 bf16x4;
typedef __attribute__((ext_vector_type(4))) float f32x4;

static __device__ __forceinline__ ushort f2bf(float f) {
  union { float f; uint32_t u; } v; v.f = f;
  uint32_t u = v.u;
  u += 0x7fffu + ((u >> 16) & 1u);
  return (ushort)(u >> 16);
}

// raw v_exp_f32 (2^x): single transcendental, no OCML range fixup.
static __device__ __forceinline__ float fast_exp2(float x) {
  float r;
  asm("v_exp_f32 %0, %1" : "=v"(r) : "v"(x));
  return r;
}

// async global->LDS, 16B per lane; lds dest must be wave-uniform base
static __device__ __forceinline__ void gl_lds16(const ushort* g, ushort* l) {
  __builtin_amdgcn_global_load_lds(
      (__attribute__((address_space(1))) unsigned int*)(g),
      (__attribute__((address_space(3))) unsigned int*)(l), 16, 0, 0);
}

// ---------------- cast x (fp32) -> bf16, same layout ----------------
__global__ __launch_bounds__(256) void cast_f32_bf16(
    const float* __restrict__ in, ushort* __restrict__ out, int n) {
  int i = (blockIdx.x * 256 + threadIdx.x) * 4;
  if (i >= n) return;
  float4 v = *(const float4*)&in[i];
  ushort4 o;
  o.x = f2bf(v.x); o.y = f2bf(v.y); o.z = f2bf(v.z); o.w = f2bf(v.w);
  *(ushort4*)&out[i] = o;
}

// ------------- transpose-cast W (K x N fp32) -> Wt (N x K bf16) -------------
__global__ __launch_bounds__(256) void transpose_cast(
    const float* __restrict__ W, ushort* __restrict__ Wt, int K, int N) {
  __shared__ ushort tile[32][33];
  int n0 = blockIdx.x * 32, k0 = blockIdx.y * 32;
  int tx = threadIdx.x, ty = threadIdx.y;
  #pragma unroll
  for (int r = ty; r < 32; r += 8)
    tile[r][tx] = f2bf(W[(size_t)(k0 + r) * N + n0 + tx]);
  __syncthreads();
  #pragma unroll
  for (int r = ty; r < 32; r += 8)
    Wt[(size_t)(n0 + r) * K + k0 + tx] = tile[tx][r];
}

// ---------------- GEMM: C[M,N] = A[M,K] * Bt[N,K]^T (bf16 in, fp32 acc) ------
// BM=128, BN=128, BK=64; 256 threads = 4 waves (2Mx2N), per-wave C 64x64.
// LDS 64KB double-buffered -> 2 blocks/CU. 2 phases per K-tile, 16 MFMA each;
// counted vmcnt(4) once per tile. Chunk-XOR LDS swizzle w/ pre-swizzled src.
// MODE 1: LDS-repack epilogue -> Q*SC (B,H,T,D), K (B,H,T,D), V^T (B,H,D,T)
// MODE 2: fp32 row-major C
template <int MODE>
__global__ __launch_bounds__(256, 2) void gemm_bt(
    const ushort* __restrict__ A, const ushort* __restrict__ Bt,
    float* __restrict__ Cf, int M, int N, int K,
    ushort* __restrict__ Qo, ushort* __restrict__ Ko, ushort* __restrict__ Vo) {
  __shared__ ushort smem[32768];  // A:[2][128][64]@0 | B:[2][128][64]@16384
  const int tid = threadIdx.x;
  const int lane = tid & 63;
  const int w = tid >> 6;         // 4 waves
  const int wm = (w >> 1) * 64, wn = (w & 1) * 64;
  const int lr = lane & 15, kg = lane >> 4;
  const int fid = blockIdx.x;
  const int m0 = (((fid & 7) << 3) + ((fid >> 3) & 7)) << 7;
  const int n0 = (fid >> 6) << 7;

  auto stageA = [&](int buf, int tile, int q) {
    const int k0 = tile << 6;
    const int rowb = q * 32 + w * 8;
    gl_lds16(&A[(size_t)(m0 + rowb + (lane >> 3)) * K + k0 +
                (((lane & 7) ^ (lane >> 3)) << 3)],
             &smem[buf * 8192 + rowb * 64]);
  };
  auto stageB = [&](int buf, int tile, int q) {
    const int k0 = tile << 6;
    const int rowb = q * 32 + w * 8;
    gl_lds16(&Bt[(size_t)(n0 + rowb + (lane >> 3)) * K + k0 +
                 (((lane & 7) ^ (lane >> 3)) << 3)],
             &smem[16384 + buf * 8192 + rowb * 64]);
  };

  f32x4 zero = {0.f, 0.f, 0.f, 0.f};
  f32x4 acc[4][4];
  #pragma unroll
  for (int i = 0; i < 4; i++)
    #pragma unroll
    for (int j = 0; j < 4; j++) acc[i][j] = zero;

  const int cs0 = ((kg ^ (lr & 7)) << 3);
  const int cs1 = (((4 + kg) ^ (lr & 7)) << 3);

  const int nt = K >> 6;
  stageB(0, 0, 0); stageB(0, 0, 1); stageB(0, 0, 2); stageB(0, 0, 3);
  stageA(0, 0, 0); stageA(0, 0, 1); stageA(0, 0, 2); stageA(0, 0, 3);
  stageB(1, 1, 0); stageB(1, 1, 1); stageB(1, 1, 2); stageB(1, 1, 3);

  for (int t = 0; t < nt; ++t) {
    const int cur = t & 1, nxt = cur ^ 1;
    const int ab = cur * 8192, bbo = 16384 + cur * 8192;
    if (t + 1 < nt)
      asm volatile("s_waitcnt vmcnt(4)" ::: "memory");
    else
      asm volatile("s_waitcnt vmcnt(0)" ::: "memory");
    __builtin_amdgcn_s_barrier();
    asm volatile("" ::: "memory");
    // ---- phase 0: stage A(t+1); B frags (all) + A row-tiles 0,1 ----
    if (t + 1 < nt) {
      stageA(nxt, t + 1, 0); stageA(nxt, t + 1, 1);
      stageA(nxt, t + 1, 2); stageA(nxt, t + 1, 3);
    }
    bf16x8 bfr[4][2], af[2][2];
    #pragma unroll
    for (int j = 0; j < 4; ++j) {
      const int R = wn + j * 16 + lr;
      bfr[j][0] = *(const bf16x8*)&smem[bbo + R * 64 + cs0];
      bfr[j][1] = *(const bf16x8*)&smem[bbo + R * 64 + cs1];
    }
    #pragma unroll
    for (int il = 0; il < 2; ++il) {
      const int R = wm + il * 16 + lr;
      af[il][0] = *(const bf16x8*)&smem[ab + R * 64 + cs0];
      af[il][1] = *(const bf16x8*)&smem[ab + R * 64 + cs1];
    }
    asm volatile("s_waitcnt lgkmcnt(0)" ::: "memory");
    __builtin_amdgcn_sched_barrier(0);
    __builtin_amdgcn_s_setprio(1);
    #pragma unroll
    for (int il = 0; il < 2; ++il)
      #pragma unroll
      for (int j = 0; j < 4; ++j) {
        acc[il][j] = __builtin_amdgcn_mfma_f32_16x16x32_bf16(
            af[il][0], bfr[j][0], acc[il][j], 0, 0, 0);
        acc[il][j] = __builtin_amdgcn_mfma_f32_16x16x32_bf16(
            af[il][1], bfr[j][1], acc[il][j], 0, 0, 0);
      }
    __builtin_amdgcn_s_setprio(0);
    __builtin_amdgcn_s_barrier();
    asm volatile("" ::: "memory");
    // ---- phase 1: stage B(t+2); A rows 2,3 ----
    if (t + 2 < nt) {
      stageB(cur, t + 2, 0); stageB(cur, t + 2, 1);
      stageB(cur, t + 2, 2); stageB(cur, t + 2, 3);
    }
    bf16x8 a2[2][2];
    #pragma unroll
    for (int il = 0; il < 2; ++il) {
      const int R = wm + (2 + il) * 16 + lr;
      a2[il][0] = *(const bf16x8*)&smem[ab + R * 64 + cs0];
      a2[il][1] = *(const bf16x8*)&smem[ab + R * 64 + cs1];
    }
    asm volatile("s_waitcnt lgkmcnt(0)" ::: "memory");
    __builtin_amdgcn_sched_barrier(0);
    __builtin_amdgcn_s_setprio(1);
    #pragma unroll
    for (int il = 0; il < 2; ++il)
      #pragma unroll
      for (int j = 0; j < 4; ++j) {
        acc[2 + il][j] = __builtin_amdgcn_mfma_f32_16x16x32_bf16(
            a2[il][0], bfr[j][0], acc[2 + il][j], 0, 0, 0);
        acc[2 + il][j] = __builtin_amdgcn_mfma_f32_16x16x32_bf16(
            a2[il][1], bfr[j][1], acc[2 + il][j], 0, 0, 0);
      }
    __builtin_amdgcn_s_setprio(0);
    // loop-top barrier doubles as phase-1 trailing barrier
  }

  if (MODE == 2) {
    #pragma unroll
    for (int i = 0; i < 4; i++)
      #pragma unroll
      for (int j = 0; j < 4; j++)
        #pragma unroll
        for (int r = 0; r < 4; r++) {
          int mrow = m0 + wm + i * 16 + kg * 4 + r;
          int ncol = n0 + wn + j * 16 + lr;
          Cf[(size_t)mrow * N + ncol] = acc[i][j][r];
        }
  } else {
    __syncthreads();  // all waves done with staging LDS
    ushort* Ls = smem + w * 4608;
    const int nb = n0 + wn;
    const int which = nb >> 10;  // 0=Q 1=K 2=V (wave-uniform, 64-wide = 1 head)
    const int bb2 = (m0 + wm) >> 11;
    const int hh = (nb & 1023) >> 6;
    const size_t bh = (size_t)(bb2 * 16 + hh);
    const int t0 = (m0 + wm) & 2047;
    if (which == 2) {
      #pragma unroll
      for (int i = 0; i < 4; i++)
        #pragma unroll
        for (int j = 0; j < 4; j++)
          #pragma unroll
          for (int r = 0; r < 4; r++)
            Ls[(j * 16 + lr) * 72 + (i * 16 + kg * 4 + r)] =
                f2bf(acc[i][j][r]);
      #pragma unroll
      for (int it = 0; it < 8; it++) {
        const int cid = it * 64 + lane;
        const int d = cid >> 3, chk = cid & 7;
        bf16x8 v = *(const bf16x8*)&Ls[d * 72 + chk * 8];
        *(bf16x8*)&Vo[(bh * 64 + d) * 2048 + t0 + chk * 8] = v;
      }
    } else {
      const float sc = (which == 0) ? 0.18033688011112042f : 1.0f;
      #pragma unroll
      for (int i = 0; i < 4; i++)
        #pragma unroll
        for (int j = 0; j < 4; j++)
          #pragma unroll
          for (int r = 0; r < 4; r++)
            Ls[(i * 16 + kg * 4 + r) * 72 + (j * 16 + lr)] =
                f2bf(acc[i][j][r] * sc);
      ushort* dst = (which == 0) ? Qo : Ko;
      #pragma unroll
      for (int it = 0; it < 8; it++) {
        const int cid = it * 64 + lane;
        const int row = cid >> 3, chk = cid & 7;
        bf16x8 v = *(const bf16x8*)&Ls[row * 72 + chk * 8];
        *(bf16x8*)&dst[(bh * 2048 + t0 + row) * 64 + chk * 8] = v;
      }
    }
  }
}

// ------- flash attention (causal), 4 waves/block sharing K/V via LDS --------
// QBLK=16/wave, 64-row blocks, grid 1024 = 4 blocks/CU (16 waves/CU).
// No-max softmax (Q pre-scaled); exp2 via raw v_exp_f32; softmax denominator
// computed by MFMA with an all-ones B fragment (row-sum lands in the same
// lane/register slot as o's rows -> zero-shuffle epilogue divide).
// 2-phase double-buffered K/V staging; one barrier per KV-step.
// Q,K: (B*H, T, D) bf16 ; Vt: (B*H, D, T) bf16 ; Y: (B, T, C) bf16
__global__ __launch_bounds__(256, 4) void attn_fwd(
    const ushort* __restrict__ Q, const ushort* __restrict__ Kc,
    const ushort* __restrict__ Vt, ushort* __restrict__ Y) {
  __shared__ ushort Ks[2][64][64];  // [k][d], 16B-chunk XOR-swizzled
  __shared__ ushort Vs[2][64][64];  // [d][k], 16B-chunk XOR-swizzled
  __shared__ ushort Ps[4][16][64];  // per-wave P, [q][k], XOR-swizzled
  const int tid = threadIdx.x;
  const int lane = tid & 63, w = tid >> 6;
  const int lr = lane & 15, kg = lane >> 4;
  int blk = blockIdx.x;
  blk = (blk & 7) * 128 + (blk >> 3);  // XCD-chunked (1024 % 8 == 0)
  const int pair = blk & 15;
  const int bh = blk >> 4;
  const ushort* Qp = Q + (size_t)bh * 2048 * 64;
  const ushort* Kp = Kc + (size_t)bh * 2048 * 64;
  const ushort* Vp = Vt + (size_t)bh * 64 * 2048;
  const int b = bh >> 4, h = bh & 15;
  const int swz = (lr & 14) << 3;  // P-tile swizzle (bytes)
  char* PsB = (char*)&Ps[w][0][0];
  const int srow = lane >> 3, schunk = lane & 7;
  const int cs0 = (kg ^ (lr & 7)) << 3;
  const int cs1 = ((kg ^ 4) ^ (lr & 7)) << 3;
  f32x4 zero = {0.f, 0.f, 0.f, 0.f};
  bf16x8 ones;
  #pragma unroll
  for (int i = 0; i < 8; i++) ones[i] = (__bf16)1.0f;

  auto stageKV = [&](int buf, int k0) {
    #pragma unroll
    for (int c = 0; c < 2; c++) {
      const int rbase = w * 16 + c * 8;
      const int r = rbase + srow;
      gl_lds16(&Kp[(size_t)(k0 + r) * 64 + ((schunk ^ (r & 7)) << 3)],
               &Ks[buf][rbase][0]);
      gl_lds16(&Vp[(size_t)r * 2048 + k0 + ((schunk ^ (r & 7)) << 3)],
               &Vs[buf][rbase][0]);
    }
  };

  for (int half = 0; half < 2; half++) {
    const int j = half ? (31 - pair) : pair;
    const int q0b = j << 6;
    const int qw0 = q0b + w * 16;
    bf16x8 qf0 = *(const bf16x8*)&Qp[(size_t)(qw0 + lr) * 64 + kg * 8];
    bf16x8 qf1 = *(const bf16x8*)&Qp[(size_t)(qw0 + lr) * 64 + 32 + kg * 8];
    f32x4 o[4];
    #pragma unroll
    for (int dt = 0; dt < 4; dt++) o[dt] = zero;
    f32x4 ol = zero;  // softmax denominator (rows match o's rows)

    stageKV(0, 0);
    __syncthreads();  // prologue KV tile resident
    for (int k0 = 0; k0 <= q0b; k0 += 64) {
      const int cur = (k0 >> 6) & 1;
      if (k0 < q0b) stageKV(cur ^ 1, k0 + 64);  // in flight over compute

      // S^T tile: mfma(K-rows, Q-rows) -> C[k][q], lane holds q = lr
      f32x4 s[4];
      #pragma unroll
      for (int ct = 0; ct < 4; ct++) {
        bf16x8 kf0 = *(const bf16x8*)&Ks[cur][ct * 16 + lr][cs0];
        bf16x8 kf1 = *(const bf16x8*)&Ks[cur][ct * 16 + lr][cs1];
        f32x4 z = zero;
        z = __builtin_amdgcn_mfma_f32_16x16x32_bf16(kf0, qf0, z, 0, 0, 0);
        z = __builtin_amdgcn_mfma_f32_16x16x32_bf16(kf1, qf1, z, 0, 0, 0);
        s[ct] = z;
      }
      if (k0 == q0b) {  // only the last block needs the causal mask
        const int qrow = qw0 + lr;
        #pragma unroll
        for (int ct = 0; ct < 4; ct++)
          #pragma unroll
          for (int r = 0; r < 4; r++) {
            int kj = k0 + ct * 16 + kg * 4 + r;
            s[ct][r] = (kj > qrow) ? -1e30f : s[ct][r];
          }
      }
      // p = exp2(s) (raw v_exp_f32); pack bf16 into P tile
      #pragma unroll
      for (int ct = 0; ct < 4; ct++) {
        float p0 = fast_exp2(s[ct][0]);
        float p1 = fast_exp2(s[ct][1]);
        float p2 = fast_exp2(s[ct][2]);
        float p3 = fast_exp2(s[ct][3]);
        bf16x4 pk = {(__bf16)p0, (__bf16)p1, (__bf16)p2, (__bf16)p3};
        *(bf16x4*)(PsB + lr * 128 + ((ct * 32 + kg * 8) ^ swz)) = pk;
      }
      bf16x8 pa0 = *(const bf16x8*)(PsB + lr * 128 + ((kg * 16) ^ swz));
      bf16x8 pa1 = *(const bf16x8*)(PsB + lr * 128 + ((64 + kg * 16) ^ swz));
      // denominator: row-sum of P via ones-MFMA (same lane layout as o)
      ol = __builtin_amdgcn_mfma_f32_16x16x32_bf16(pa0, ones, ol, 0, 0, 0);
      ol = __builtin_amdgcn_mfma_f32_16x16x32_bf16(pa1, ones, ol, 0, 0, 0);
      #pragma unroll
      for (int dt = 0; dt < 4; dt++) {
        bf16x8 vf0 = *(const bf16x8*)&Vs[cur][dt * 16 + lr][cs0];
        bf16x8 vf1 = *(const bf16x8*)&Vs[cur][dt * 16 + lr][cs1];
        f32x4 t = o[dt];
        t = __builtin_amdgcn_mfma_f32_16x16x32_bf16(pa0, vf0, t, 0, 0, 0);
        t = __builtin_amdgcn_mfma_f32_16x16x32_bf16(pa1, vf1, t, 0, 0, 0);
        o[dt] = t;
      }
      __syncthreads();  // drains vmcnt (next KV ready) + protects reads
    }

    // epilogue: divide by per-row denominator (no shuffles), write Y
    f32x4 ib;
    #pragma unroll
    for (int r = 0; r < 4; r++) ib[r] = 1.f / ol[r];
    #pragma unroll
    for (int dt = 0; dt < 4; dt++) {
      #pragma unroll
      for (int r = 0; r < 4; r++) {
        size_t t = (size_t)qw0 + kg * 4 + r;
        Y[((size_t)b * 2048 + t) * 1024 + h * 64 + dt * 16 + lr] =
            f2bf(o[dt][r] * ib[r]);
      }
    }
  }
}

extern "C" void kernel_launch(void* const* d_in, const int* in_sizes, int n_in,
                              void* d_out, int out_size, void* d_ws,
                              size_t ws_size, hipStream_t stream) {
  const float* x = (const float*)d_in[0];
  const float* Wa = (const float*)d_in[1];
  const float* Wp = (const float*)d_in[2];
  float* out = (float*)d_out;

  char* ws = (char*)d_ws;
  size_t off = 0;
  auto carve = [&](size_t bytes) {
    void* p = ws + off;
    off += (bytes + 255) & ~(size_t)255;
    return p;
  };
  ushort* Xb = (ushort*)carve(8192ull * 1024 * 2);
  ushort* Wat = (ushort*)carve(3072ull * 1024 * 2);
  ushort* Wpt = (ushort*)carve(1024ull * 1024 * 2);
  ushort* Qh = (ushort*)carve(64ull * 2048 * 64 * 2);
  ushort* Kh = (ushort*)carve(64ull * 2048 * 64 * 2);
  ushort* Vt = (ushort*)carve(64ull * 64 * 2048 * 2);
  ushort* Yb = (ushort*)carve(8192ull * 1024 * 2);

  cast_f32_bf16<<<8192, 256, 0, stream>>>(x, Xb, 8192 * 1024);
  transpose_cast<<<dim3(96, 32), dim3(32, 8), 0, stream>>>(Wa, Wat, 1024, 3072);
  transpose_cast<<<dim3(32, 32), dim3(32, 8), 0, stream>>>(Wp, Wpt, 1024, 1024);
  gemm_bt<1><<<1536, 256, 0, stream>>>(Xb, Wat, nullptr, 8192, 3072, 1024, Qh,
                                       Kh, Vt);
  attn_fwd<<<1024, 256, 0, stream>>>(Qh, Kh, Vt, Yb);
  gemm_bt<2><<<512, 256, 0, stream>>>(Yb, Wpt, out, 8192, 1024, 1024, nullptr,
                                      nullptr, nullptr);
}